// Round 1
// baseline (233.879 us; speedup 1.0000x reference)
//
#include <hip/hip_runtime.h>

#define NTAG 64
#define TLEN 512
#define START_TAG 62
#define STOP_TAG 63

__device__ __forceinline__ float bcast_lane(float v, int k) {
    return __uint_as_float(__builtin_amdgcn_readlane(__float_as_uint(v), k));
}

// One workgroup (128 threads = 2 waves) per batch element.
// wave 0: forward recursion over t = 0..T/2-1
// wave 1: backward recursion over t = T-1..T/2
// combine: out[b] = logsumexp(alpha_half + beta_half)
//
// Per-step math (log-domain with running offset c = value at lane 0):
//   p[k]    = exp(fv[k] - c)             (one v_exp per wave)
//   s[lane] = sum_k p[k] * E[lane][k]    (E = exp(trans), constant, in VGPRs;
//                                         p[k] broadcast via v_readlane)
//   fv'     = c + ln2*log2(s) + emit     (one v_log per wave)
__global__ __launch_bounds__(128) void crf_fwd_bwd(
    const float* __restrict__ emis,   // [B, T, L]
    const float* __restrict__ trans,  // [L, L]  trans[next, prev]
    float* __restrict__ out)          // [B]
{
    const int b    = blockIdx.x;
    const int tid  = threadIdx.x;
    const int lane = tid & 63;
    const int w    = tid >> 6;  // 0 = forward, 1 = backward

    __shared__ float sh[2][NTAG];

    const float L2E = 1.4426950408889634f;
    const float LN2 = 0.6931471805599453f;

    // Per-lane transition row, exponentiated, held in 64 VGPRs.
    //   fwd: E[k] = exp(trans[lane, k])  (reduce over prev = k)
    //   bwd: E[k] = exp(trans[k, lane])  (reduce over next = k)
    float E[NTAG];
    if (w == 0) {
        // row-major row: per-lane contiguous -> float4 loads
        const float4* rowp = (const float4*)(trans + lane * NTAG);
        #pragma unroll
        for (int k4 = 0; k4 < NTAG / 4; ++k4) {
            float4 v = rowp[k4];
            E[4 * k4 + 0] = exp2f(v.x * L2E);
            E[4 * k4 + 1] = exp2f(v.y * L2E);
            E[4 * k4 + 2] = exp2f(v.z * L2E);
            E[4 * k4 + 3] = exp2f(v.w * L2E);
        }
    } else {
        // column: each load is lane-contiguous (coalesced)
        #pragma unroll
        for (int k = 0; k < NTAG; ++k)
            E[k] = exp2f(trans[k * NTAG + lane] * L2E);
    }

    const float* eb = emis + (size_t)b * TLEN * NTAG;

    float fv;
    int nsteps;
    const float* ep;
    long estride;
    float preW, postW;  // bwd adds emission before the lse, fwd after
    if (w == 0) {
        // fold t=0 into init: fv_1[n] = trans[n, START] + emit_0[n]
        // (exact in fp32: all other init terms are exp(-10000+x) == 0)
        fv      = trans[lane * NTAG + START_TAG] + eb[lane];
        nsteps  = TLEN / 2 - 1;          // t = 1 .. 255
        ep      = eb + NTAG;             // t = 1
        estride = NTAG;
        preW = 0.0f; postW = 1.0f;
    } else {
        fv      = trans[STOP_TAG * NTAG + lane];  // beta_T[p] = trans[STOP, p]
        nsteps  = TLEN / 2;              // t = 511 .. 256
        ep      = eb + (size_t)(TLEN - 1) * NTAG; // t = 511
        estride = -NTAG;
        preW = 1.0f; postW = 0.0f;
    }

    // software-pipelined emission loads (distance 2) to hide HBM latency
    float e0 = ep[lane];
    float e1 = ep[estride + lane];

    for (int i = 0; i < nsteps; ++i) {
        float em = e0;
        e0 = e1;
        long j = (long)(i + 2 < nsteps ? i + 2 : nsteps - 1);
        e1 = ep[j * estride + lane];

        float g = fmaf(preW, em, fv);
        float c = bcast_lane(g, 0);           // finite: lane 0 is never masked
        float p = exp2f((g - c) * L2E);       // p[lane] in [0, ~2e5]

        float a0 = 0.f, a1 = 0.f, a2 = 0.f, a3 = 0.f;
        #pragma unroll
        for (int k = 0; k < NTAG; k += 4) {
            a0 = fmaf(bcast_lane(p, k + 0), E[k + 0], a0);
            a1 = fmaf(bcast_lane(p, k + 1), E[k + 1], a1);
            a2 = fmaf(bcast_lane(p, k + 2), E[k + 2], a2);
            a3 = fmaf(bcast_lane(p, k + 3), E[k + 3], a3);
        }
        float s = (a0 + a1) + (a2 + a3);      // 0 only in masked lanes -> -inf, safe

        fv = fmaf(postW, em, fmaf(LN2, log2f(s), c));
    }

    sh[w][lane] = fv;
    __syncthreads();

    if (w == 0) {
        float v = sh[0][lane] + sh[1][lane];
        float m = v;
        #pragma unroll
        for (int d = 1; d < 64; d <<= 1) m = fmaxf(m, __shfl_xor(m, d, 64));
        float e = exp2f((v - m) * L2E);
        #pragma unroll
        for (int d = 1; d < 64; d <<= 1) e += __shfl_xor(e, d, 64);
        if (lane == 0) out[b] = fmaf(LN2, log2f(e), m);
    }
}

extern "C" void kernel_launch(void* const* d_in, const int* in_sizes, int n_in,
                              void* d_out, int out_size, void* d_ws, size_t ws_size,
                              hipStream_t stream) {
    const float* emis  = (const float*)d_in[0];   // [512, 512, 64] f32
    const float* trans = (const float*)d_in[1];   // [64, 64] f32
    float* out = (float*)d_out;                   // [512] f32
    (void)in_sizes; (void)n_in; (void)out_size; (void)d_ws; (void)ws_size;
    crf_fwd_bwd<<<512, 128, 0, stream>>>(emis, trans, out);
}

// Round 2
// 201.808 us; speedup vs baseline: 1.1589x; 1.1589x over previous
//
#include <hip/hip_runtime.h>

#define NTAG 64
#define TLEN 512
#define START_TAG 62
#define STOP_TAG 63
#define CHUNK 32          // timesteps staged per LDS buffer
#define HALF (TLEN / 2)   // 256 steps per direction

__device__ __forceinline__ float bcast_lane(float v, int k) {
    return __uint_as_float(__builtin_amdgcn_readlane(__float_as_uint(v), k));
}

// One workgroup (128 threads = 2 waves) per batch element.
//   wave 0: forward recursion  t = 0..255   (t=0 folded into init)
//   wave 1: backward recursion t = 511..256
//   out[b] = logsumexp(alpha_half + beta_half)
//
// Round-2 changes vs round 1 (which stalled ~1300 cyc/step on exposed
// per-step global-load latency at 1 wave/SIMD):
//   - emissions staged in LDS, 32 timesteps/chunk, double-buffered; global
//     float4 loads for chunk ci+1 are issued a full chunk (~10K cyc) before
//     use -> HBM/L3 latency fully hidden, one vmcnt wait per 32 steps
//   - per-step emission via ds_read_b32 prefetched 1 step ahead (2-way bank
//     alias = free on gfx950)
//   - fwd/bwd loops specialized (no preW/postW fma, no 64-bit index mul)
__global__ __launch_bounds__(128) void crf_fwd_bwd(
    const float* __restrict__ emis,   // [B, T, L]
    const float* __restrict__ trans,  // [L, L]  trans[next, prev]
    float* __restrict__ out)          // [B]
{
    const int b    = blockIdx.x;
    const int tid  = threadIdx.x;
    const int lane = tid & 63;
    const int w    = tid >> 6;  // 0 = forward, 1 = backward

    // [wave][buf][CHUNK*NTAG] : 2*2*2048 floats = 32 KB
    __shared__ float lds[2 * 2 * CHUNK * NTAG];
    __shared__ float sh[2][NTAG];

    const float L2E = 1.4426950408889634f;
    const float LN2 = 0.6931471805599453f;

    // Per-lane transition row, exponentiated, held in 64 VGPRs.
    //   fwd: E[k] = exp(trans[lane, k])  (reduce over prev = k)
    //   bwd: E[k] = exp(trans[k, lane])  (reduce over next = k)
    float E[NTAG];
    if (w == 0) {
        const float4* rowp = (const float4*)(trans + lane * NTAG);
        #pragma unroll
        for (int k4 = 0; k4 < NTAG / 4; ++k4) {
            float4 v = rowp[k4];
            E[4 * k4 + 0] = exp2f(v.x * L2E);
            E[4 * k4 + 1] = exp2f(v.y * L2E);
            E[4 * k4 + 2] = exp2f(v.z * L2E);
            E[4 * k4 + 3] = exp2f(v.w * L2E);
        }
    } else {
        #pragma unroll
        for (int k = 0; k < NTAG; ++k)
            E[k] = exp2f(trans[k * NTAG + lane] * L2E);
    }

    const float* eb = emis + (size_t)b * TLEN * NTAG;

    // chunk-staging registers: 8 float4 = one wave covers CHUNK*NTAG floats
    float4 r0, r1, r2, r3, r4, r5, r6, r7;
    #define LOAD_CHUNK(baseT)                                      \
        do {                                                       \
            const float4* gp = (const float4*)(eb + (baseT) * NTAG); \
            r0 = gp[0 * 64 + lane]; r1 = gp[1 * 64 + lane];        \
            r2 = gp[2 * 64 + lane]; r3 = gp[3 * 64 + lane];        \
            r4 = gp[4 * 64 + lane]; r5 = gp[5 * 64 + lane];        \
            r6 = gp[6 * 64 + lane]; r7 = gp[7 * 64 + lane];        \
        } while (0)

    #define STORE_CHUNK(bufp)                                      \
        do {                                                       \
            float4* b4 = (float4*)(bufp);                          \
            b4[0 * 64 + lane] = r0; b4[1 * 64 + lane] = r1;        \
            b4[2 * 64 + lane] = r2; b4[3 * 64 + lane] = r3;        \
            b4[4 * 64 + lane] = r4; b4[5 * 64 + lane] = r5;        \
            b4[6 * 64 + lane] = r6; b4[7 * 64 + lane] = r7;        \
        } while (0)

    #define MATVEC(p, ssum)                                        \
        do {                                                       \
            float a0 = 0.f, a1 = 0.f, a2 = 0.f, a3 = 0.f;          \
            float a4 = 0.f, a5 = 0.f, a6 = 0.f, a7 = 0.f;          \
            _Pragma("unroll")                                      \
            for (int k = 0; k < NTAG; k += 8) {                    \
                a0 = fmaf(bcast_lane(p, k + 0), E[k + 0], a0);     \
                a1 = fmaf(bcast_lane(p, k + 1), E[k + 1], a1);     \
                a2 = fmaf(bcast_lane(p, k + 2), E[k + 2], a2);     \
                a3 = fmaf(bcast_lane(p, k + 3), E[k + 3], a3);     \
                a4 = fmaf(bcast_lane(p, k + 4), E[k + 4], a4);     \
                a5 = fmaf(bcast_lane(p, k + 5), E[k + 5], a5);     \
                a6 = fmaf(bcast_lane(p, k + 6), E[k + 6], a6);     \
                a7 = fmaf(bcast_lane(p, k + 7), E[k + 7], a7);     \
            }                                                      \
            ssum = ((a0 + a1) + (a2 + a3)) + ((a4 + a5) + (a6 + a7)); \
        } while (0)

    float fv;
    if (w == 0) {
        // fold t=0 into init: fv_1[n] = trans[n, START] + emit_0[n]
        fv = trans[lane * NTAG + START_TAG] + eb[lane];

        LOAD_CHUNK(0);
        for (int ci = 0; ci < 8; ++ci) {
            float* buf = &lds[(ci & 1) * (CHUNK * NTAG)];
            STORE_CHUNK(buf);
            if (ci < 7) LOAD_CHUNK((ci + 1) * CHUNK);  // in flight ~32 steps

            const int s0 = (ci == 0) ? 1 : 0;  // t=0 already folded in
            float em = buf[s0 * NTAG + lane];
            for (int s = s0; s < CHUNK; ++s) {
                const int sn = (s + 1 < CHUNK) ? (s + 1) : s;
                float em_next = buf[sn * NTAG + lane];  // prefetch

                float c = bcast_lane(fv, 0);            // lane 0 never masked
                float p = exp2f((fv - c) * L2E);
                float ssum;
                MATVEC(p, ssum);
                fv = fmaf(LN2, log2f(ssum), c) + em;

                em = em_next;
            }
        }
    } else {
        fv = trans[STOP_TAG * NTAG + lane];  // beta_T[p] = trans[STOP, p]

        LOAD_CHUNK(HALF + 7 * CHUNK);
        for (int i = 0; i < 8; ++i) {
            const int ci = 7 - i;                       // consume descending
            float* buf = &lds[(2 + (i & 1)) * (CHUNK * NTAG)];
            STORE_CHUNK(buf);
            if (i < 7) LOAD_CHUNK(HALF + (ci - 1) * CHUNK);

            float em = buf[(CHUNK - 1) * NTAG + lane];
            for (int s = CHUNK - 1; s >= 0; --s) {
                const int sn = (s > 0) ? (s - 1) : s;
                float em_next = buf[sn * NTAG + lane];  // prefetch

                float g = fv + em;
                float c = bcast_lane(g, 0);
                float p = exp2f((g - c) * L2E);
                float ssum;
                MATVEC(p, ssum);
                fv = fmaf(LN2, log2f(ssum), c);

                em = em_next;
            }
        }
    }

    sh[w][lane] = fv;
    __syncthreads();

    if (w == 0) {
        float v = sh[0][lane] + sh[1][lane];
        float m = v;
        #pragma unroll
        for (int d = 1; d < 64; d <<= 1) m = fmaxf(m, __shfl_xor(m, d, 64));
        float e = exp2f((v - m) * L2E);
        #pragma unroll
        for (int d = 1; d < 64; d <<= 1) e += __shfl_xor(e, d, 64);
        if (lane == 0) out[b] = fmaf(LN2, log2f(e), m);
    }
}

extern "C" void kernel_launch(void* const* d_in, const int* in_sizes, int n_in,
                              void* d_out, int out_size, void* d_ws, size_t ws_size,
                              hipStream_t stream) {
    const float* emis  = (const float*)d_in[0];   // [512, 512, 64] f32
    const float* trans = (const float*)d_in[1];   // [64, 64] f32
    float* out = (float*)d_out;                   // [512] f32
    (void)in_sizes; (void)n_in; (void)out_size; (void)d_ws; (void)ws_size;
    crf_fwd_bwd<<<512, 128, 0, stream>>>(emis, trans, out);
}

// Round 3
// 185.946 us; speedup vs baseline: 1.2578x; 1.0853x over previous
//
#include <hip/hip_runtime.h>

#define NTAG 64
#define TLEN 512
#define START_TAG 62
#define STOP_TAG 63
#define CHUNK 32          // timesteps staged per LDS buffer
#define HALF (TLEN / 2)   // 256 steps per direction

__device__ __forceinline__ float bcast_lane(float v, int k) {
    return __uint_as_float(__builtin_amdgcn_readlane(__float_as_uint(v), k));
}

// One workgroup (128 threads = 2 waves) per batch element.
//   wave 0: forward  a_{t+1}[n] = (sum_p E[n,p] a_t[p]) * w_t[n],  t=0..255
//   wave 1: backward b_t[p]     =  sum_n E[n,p] (w_t[n] b_{t+1}[n]), t=511..256
// with E = exp(trans) constant in VGPRs and w_t = exp(emis_t) precomputed
// into LDS at staging time. LINEAR domain: no exp/log in the recurrence
// (round-2 postmortem: the per-step readlane->exp->matvec->log serial chain
// was ~800 cyc/step of pure stall at 1 wave/SIMD). Exact power-of-2 renorm
// every 4 steps bounds the dynamic range (growth <= ~2^15/step).
// out[b] = ln(sum_tag a_half * b_half) + ln2*(off_a + off_b).
__global__ __launch_bounds__(128) void crf_fwd_bwd(
    const float* __restrict__ emis,   // [B, T, L]
    const float* __restrict__ trans,  // [L, L]  trans[next, prev]
    float* __restrict__ out)          // [B]
{
    const int b    = blockIdx.x;
    const int tid  = threadIdx.x;
    const int lane = tid & 63;
    const int w    = tid >> 6;  // 0 = forward, 1 = backward

    // [wave][buf][CHUNK*NTAG] : 2*2*2048 floats = 32 KB (holds exp(emis))
    __shared__ float lds[2 * 2 * CHUNK * NTAG];
    __shared__ float sh[2][NTAG];

    const float L2E = 1.4426950408889634f;
    const float LN2 = 0.6931471805599453f;

    // Per-lane transition row, exponentiated, held in 64 VGPRs.
    //   fwd: E[k] = exp(trans[lane, k])  (reduce over prev = k)
    //   bwd: E[k] = exp(trans[k, lane])  (reduce over next = k)
    // Masked entries (-10000) flush to exactly 0.
    float E[NTAG];
    if (w == 0) {
        const float4* rowp = (const float4*)(trans + lane * NTAG);
        #pragma unroll
        for (int k4 = 0; k4 < NTAG / 4; ++k4) {
            float4 v = rowp[k4];
            E[4 * k4 + 0] = exp2f(v.x * L2E);
            E[4 * k4 + 1] = exp2f(v.y * L2E);
            E[4 * k4 + 2] = exp2f(v.z * L2E);
            E[4 * k4 + 3] = exp2f(v.w * L2E);
        }
    } else {
        #pragma unroll
        for (int k = 0; k < NTAG; ++k)
            E[k] = exp2f(trans[k * NTAG + lane] * L2E);
    }

    const float* eb = emis + (size_t)b * TLEN * NTAG;

    // chunk staging: 8 float4/lane covers CHUNK*NTAG floats per chunk
    float4 r0, r1, r2, r3, r4, r5, r6, r7;
    #define LOAD_CHUNK(baseT)                                        \
        do {                                                         \
            const float4* gp = (const float4*)(eb + (baseT) * NTAG); \
            r0 = gp[0 * 64 + lane]; r1 = gp[1 * 64 + lane];          \
            r2 = gp[2 * 64 + lane]; r3 = gp[3 * 64 + lane];          \
            r4 = gp[4 * 64 + lane]; r5 = gp[5 * 64 + lane];          \
            r6 = gp[6 * 64 + lane]; r7 = gp[7 * 64 + lane];          \
        } while (0)

    // exp() applied at store time: w = exp(emis) lands in LDS; the 32
    // quarter-rate v_exp per chunk are OFF the recurrence's critical path.
    #define EXP4(v) make_float4(exp2f((v).x * L2E), exp2f((v).y * L2E), \
                                exp2f((v).z * L2E), exp2f((v).w * L2E))
    #define STORE_CHUNK_EXP(bufp)                                    \
        do {                                                         \
            float4* b4 = (float4*)(bufp);                            \
            b4[0 * 64 + lane] = EXP4(r0); b4[1 * 64 + lane] = EXP4(r1); \
            b4[2 * 64 + lane] = EXP4(r2); b4[3 * 64 + lane] = EXP4(r3); \
            b4[4 * 64 + lane] = EXP4(r4); b4[5 * 64 + lane] = EXP4(r5); \
            b4[6 * 64 + lane] = EXP4(r6); b4[7 * 64 + lane] = EXP4(r7); \
        } while (0)

    #define MATVEC(p, ssum)                                          \
        do {                                                         \
            float a0 = 0.f, a1 = 0.f, a2 = 0.f, a3 = 0.f;            \
            float a4 = 0.f, a5 = 0.f, a6 = 0.f, a7 = 0.f;            \
            _Pragma("unroll")                                        \
            for (int k = 0; k < NTAG; k += 8) {                      \
                a0 = fmaf(bcast_lane(p, k + 0), E[k + 0], a0);       \
                a1 = fmaf(bcast_lane(p, k + 1), E[k + 1], a1);       \
                a2 = fmaf(bcast_lane(p, k + 2), E[k + 2], a2);       \
                a3 = fmaf(bcast_lane(p, k + 3), E[k + 3], a3);       \
                a4 = fmaf(bcast_lane(p, k + 4), E[k + 4], a4);       \
                a5 = fmaf(bcast_lane(p, k + 5), E[k + 5], a5);       \
                a6 = fmaf(bcast_lane(p, k + 6), E[k + 6], a6);       \
                a7 = fmaf(bcast_lane(p, k + 7), E[k + 7], a7);       \
            }                                                        \
            ssum = ((a0 + a1) + (a2 + a3)) + ((a4 + a5) + (a6 + a7)); \
        } while (0)

    // exact power-of-2 renorm: scale so lane-0's exponent returns to 0.
    // lane 0 (tag 0) is never masked and is within e^12 of the max.
    #define RENORM(x, off)                                                 \
        do {                                                               \
            unsigned _bb = __builtin_amdgcn_readlane(__float_as_uint(x), 0); \
            int _e = (int)((_bb >> 23) & 0xffu) - 127;                     \
            off += _e;                                                     \
            x *= __uint_as_float((unsigned)(127 - _e) << 23);              \
        } while (0)

    float x;        // recursion state, one tag per lane
    int   off = 0;  // accumulated power-of-2 offset (exact)

    if (w == 0) {
        x = (lane == START_TAG) ? 1.0f : 0.0f;  // a_0 = exp(init)

        LOAD_CHUNK(0);
        for (int ci = 0; ci < 8; ++ci) {
            float* buf = &lds[(ci & 1) * (CHUNK * NTAG)];
            STORE_CHUNK_EXP(buf);
            if (ci < 7) LOAD_CHUNK((ci + 1) * CHUNK);  // in flight ~32 steps

            float wcur = buf[lane];
            #pragma unroll
            for (int sg = 0; sg < 8; ++sg) {
                #pragma unroll
                for (int q = 0; q < 4; ++q) {
                    const int s  = sg * 4 + q;
                    const int sn = (s + 1 < CHUNK) ? s + 1 : s;
                    float wnext = buf[sn * NTAG + lane];  // prefetch
                    float ssum;
                    MATVEC(x, ssum);
                    x = ssum * wcur;
                    wcur = wnext;
                }
                RENORM(x, off);
            }
        }
    } else {
        x = exp2f(trans[STOP_TAG * NTAG + lane] * L2E);  // b_T = exp(trans[STOP,:])

        LOAD_CHUNK(HALF + 7 * CHUNK);
        for (int i = 0; i < 8; ++i) {
            const int ci = 7 - i;                         // consume descending t
            float* buf = &lds[(2 + (i & 1)) * (CHUNK * NTAG)];
            STORE_CHUNK_EXP(buf);
            if (i < 7) LOAD_CHUNK(HALF + (ci - 1) * CHUNK);

            float wcur = buf[(CHUNK - 1) * NTAG + lane];
            #pragma unroll
            for (int sg = 0; sg < 8; ++sg) {
                #pragma unroll
                for (int q = 0; q < 4; ++q) {
                    const int s  = CHUNK - 1 - (sg * 4 + q);
                    const int sn = (s > 0) ? s - 1 : 0;
                    float wnext = buf[sn * NTAG + lane];  // prefetch
                    float u = x * wcur;
                    float ssum;
                    MATVEC(u, ssum);
                    x = ssum;
                    wcur = wnext;
                }
                RENORM(x, off);
            }
        }
    }

    // back to log2 domain once, merge the two half-chains
    sh[w][lane] = log2f(x) + (float)off;   // -inf for masked tags, safe
    __syncthreads();

    if (w == 0) {
        float v = sh[0][lane] + sh[1][lane];
        float m = v;
        #pragma unroll
        for (int d = 1; d < 64; d <<= 1) m = fmaxf(m, __shfl_xor(m, d, 64));
        float e = exp2f(v - m);
        #pragma unroll
        for (int d = 1; d < 64; d <<= 1) e += __shfl_xor(e, d, 64);
        if (lane == 0) out[b] = LN2 * (m + log2f(e));
    }
}

extern "C" void kernel_launch(void* const* d_in, const int* in_sizes, int n_in,
                              void* d_out, int out_size, void* d_ws, size_t ws_size,
                              hipStream_t stream) {
    const float* emis  = (const float*)d_in[0];   // [512, 512, 64] f32
    const float* trans = (const float*)d_in[1];   // [64, 64] f32
    float* out = (float*)d_out;                   // [512] f32
    (void)in_sizes; (void)n_in; (void)out_size; (void)d_ws; (void)ws_size;
    crf_fwd_bwd<<<512, 128, 0, stream>>>(emis, trans, out);
}